// Round 11
// baseline (86.823 us; speedup 1.0000x reference)
//
#include <hip/hip_runtime.h>

#define NBINS 64
#define NGRAPH 64
#define HID 256
#define TJ 128              // j-tile (staged in LDS)
#define NBLK 20             // blocks per graph (i-tile 256 x j-tile 128, i<j)
#define BPG NBLK
#define PPW 5               // partials summed per wave in mlp (20 = 4*5)
#define NSUB 32             // sub-histograms (8 per wave)
#define HSTR 65             // 64 real bins + trash bin 64; sub-major stride

// block table: i-tile I (256 rows), j-tile J (128 cols); FULL iff all i<j
__device__ __constant__ unsigned char itab[NBLK] = {
  0,0,0,0,0,0,0,0, 1,1,1,1,1,1, 2,2,2,2, 3,3};
__device__ __constant__ unsigned char jtab[NBLK] = {
  0,1,2,3,4,5,6,7, 2,3,4,5,6,7, 4,5,6,7, 6,7};

// Inner loop: 1 uniform j-broadcast feeds 4 i-pairs (halves ds_read count).
// Positions pre-scaled by 2.56 so bin=(int)sqrt(d2); d>=25 or masked pairs
// land in trash bin 64 (dropped at flush).
template <bool FULL>
__device__ __forceinline__ void pair_loop(const float4* __restrict__ plj,
                                          unsigned int* __restrict__ hw,
                                          const float4* p, int irel, int jbase) {
  #pragma unroll 4
  for (int jj = 0; jj < 32; ++jj) {
    int jl = jbase + jj;
    float4 pj = plj[jl];                  // wave-uniform broadcast ds_read_b128
    #pragma unroll
    for (int m = 0; m < 4; ++m) {
      float dx = p[m].x - pj.x, dy = p[m].y - pj.y, dz = p[m].z - pj.z;
      float d2 = dx * dx + dy * dy + dz * dz;
      unsigned int b = (unsigned int)(int)__builtin_amdgcn_sqrtf(d2);
      b = b > 64u ? 64u : b;              // v_min_u32
      if (!FULL) b = (irel + m < jl) ? b : 64u;  // route i>=j to trash
      atomicAdd(&hw[b], 1u);              // unconditional ds_add_u32
    }
  }
}

// -------- Kernel 1: tiled pairwise-distance histogram (i<j exactly once) ----
__global__ __launch_bounds__(256) void hist_kernel(const float* __restrict__ pos,
                                                   unsigned int* __restrict__ partial) {
  int bid = blockIdx.x;
  int g   = bid / NBLK;
  int p   = bid - g * NBLK;
  int ti  = itab[p];
  int tj  = jtab[p];
  bool full = (tj >= 2 * ti + 2);
  int t   = threadIdx.x;
  const float S = 2.56f;                  // NBINS / MAX_DIST

  __shared__ float4 plj[TJ];                   // 2 KB j-tile (pre-scaled)
  __shared__ unsigned int h[NSUB * HSTR];      // 8.3 KB sub-histograms

  for (int k = t; k < NSUB * HSTR; k += 256) h[k] = 0u;
  if (t < TJ) {
    const float* gp = pos + (size_t)((g << 10) + (tj << 7) + t) * 3;
    plj[t] = make_float4(gp[0] * S, gp[1] * S, gp[2] * S, 0.0f);
  }

  // thread t: 4 i's (rows (t&63)*4..+3 of i-tile), j-quarter per wave
  int il = (t & 63) << 2;
  const float* ip = pos + (size_t)((g << 10) + (ti << 8) + il) * 3;
  float4 A = *(const float4*)(ip);        // x0 y0 z0 x1
  float4 Bv = *(const float4*)(ip + 4);   // y1 z1 x2 y2
  float4 C = *(const float4*)(ip + 8);    // z2 x3 y3 z3
  float4 pp[4];
  pp[0] = make_float4(A.x * S, A.y * S, A.z * S, 0.f);
  pp[1] = make_float4(A.w * S, Bv.x * S, Bv.y * S, 0.f);
  pp[2] = make_float4(Bv.z * S, Bv.w * S, C.x * S, 0.f);
  pp[3] = make_float4(C.y * S, C.z * S, C.w * S, 0.f);
  int irel  = (ti << 8) + il - (tj << 7); // i - j_tile_base (for predicate)
  int jbase = (t >> 6) * 32;              // uniform per wave
  unsigned int* hw = h + ((t >> 6) * 8 + (t & 7)) * HSTR;
  __syncthreads();

  if (full) pair_loop<true >(plj, hw, pp, irel, jbase);
  else      pair_loop<false>(plj, hw, pp, irel, jbase);
  __syncthreads();

  if (t < NBINS) {                        // flush (trash bin 64 dropped)
    unsigned int s = 0u;
    #pragma unroll
    for (int k = 0; k < NSUB; ++k) s += h[k * HSTR + t];
    partial[(size_t)bid * NBINS + t] = s;
  }
}

// -------- Kernel 2: partial-sum + normalize + 2-layer MLP --------
// Block = (graph, output-quarter). Partial-sum parallel across 4 waves.
__global__ __launch_bounds__(256) void mlp_kernel(const unsigned int* __restrict__ partial,
                                                  const float* __restrict__ W1,
                                                  const float* __restrict__ b1,
                                                  const float* __restrict__ W2,
                                                  const float* __restrict__ b2,
                                                  float* __restrict__ out) {
  int g = blockIdx.x >> 2;
  int q = blockIdx.x & 3;
  int t = threadIdx.x;
  int w = t >> 6, l = t & 63;
  __shared__ float psum[4][NBINS];
  __shared__ float hn[NBINS];
  __shared__ float h1[HID];
  __shared__ float p2[4][NBINS];

  { // each wave sums PPW partials for its bin l
    unsigned int s = 0u;
    const unsigned int* pp = partial + (size_t)g * BPG * NBINS + l;
    #pragma unroll
    for (int k = 0; k < PPW; ++k) s += pp[(w * PPW + k) * NBINS];
    psum[w][l] = (float)s;                // exact: < 2^23
  }
  __syncthreads();
  if (t < NBINS) {
    float hv = psum[0][t] + psum[1][t] + psum[2][t] + psum[3][t];
    float tot = hv;
    #pragma unroll
    for (int m = 1; m < 64; m <<= 1) tot += __shfl_xor(tot, m, 64);
    hn[t] = hv / (tot + 1e-8f);
  }
  __syncthreads();

  // layer 1: h1 = silu(hn @ W1^T + b1), thread t -> channel t (float4 row)
  {
    float acc = b1[t];
    const float4* wv4 = (const float4*)(W1 + (size_t)t * NBINS);
    #pragma unroll
    for (int k = 0; k < NBINS / 4; ++k) {
      float4 wv = wv4[k];
      acc += hn[4 * k] * wv.x + hn[4 * k + 1] * wv.y +
             hn[4 * k + 2] * wv.z + hn[4 * k + 3] * wv.w;
    }
    float sig = 1.0f / (1.0f + expf(-acc));
    h1[t] = acc * sig;
  }
  __syncthreads();

  // layer 2: 64 outputs (quarter q), k sliced over 4 waves
  {
    int o  = (q << 6) + l;
    int ks = w << 6;                      // 64-wide k-slice per wave
    float acc = 0.0f;
    const float4* wv4 = (const float4*)(W2 + (size_t)o * HID + ks);
    #pragma unroll
    for (int k = 0; k < 16; ++k) {
      float4 wv = wv4[k];
      acc += h1[ks + 4 * k] * wv.x + h1[ks + 4 * k + 1] * wv.y +
             h1[ks + 4 * k + 2] * wv.z + h1[ks + 4 * k + 3] * wv.w;
    }
    p2[w][l] = acc;
  }
  __syncthreads();

  if (t < 64) {
    int o = (q << 6) + t;
    out[(size_t)g * HID + o] = b2[o] + p2[0][t] + p2[1][t] + p2[2][t] + p2[3][t];
  }
}

extern "C" void kernel_launch(void* const* d_in, const int* in_sizes, int n_in,
                              void* d_out, int out_size, void* d_ws, size_t ws_size,
                              hipStream_t stream) {
  const float* pos = (const float*)d_in[0];
  const float* W1  = (const float*)d_in[1];
  const float* b1  = (const float*)d_in[2];
  const float* W2  = (const float*)d_in[3];
  const float* b2  = (const float*)d_in[4];
  // d_in[5] = batch ids: unused (contiguous equal-size segments by construction)

  unsigned int* partial = (unsigned int*)d_ws; // 1280 * 64 * 4 = 327 KB scratch

  hipLaunchKernelGGL(hist_kernel, dim3(NGRAPH * NBLK), dim3(256), 0, stream, pos, partial);
  hipLaunchKernelGGL(mlp_kernel, dim3(NGRAPH * 4), dim3(256), 0, stream,
                     partial, W1, b1, W2, b2, (float*)d_out);
}